// Round 14
// baseline (12.164 us; speedup 1.0000x reference)
//
#include <hip/hip_runtime.h>

constexpr int NPIX = 360 * 640;            // 230400 = 3600 * 64 exactly
constexpr int NSQ = 8, NSAMP = 10;
constexpr float FARV = 1.5f;
constexpr float SHARPV = 1000.0f;
constexpr float TAU2 = 100.0f * 1.44269504f;   // TAU * log2(e)
constexpr float DT9 = 2.0f / 9.0f;
constexpr float T2_18 = 49.0f / 81.0f;     // t^2 at samples k=1,8
constexpr float T2_27 = 25.0f / 81.0f;     // t^2 at samples k=2,7

struct SQT {
  float A[9];      // R * diag(1/s):  w_j = sum_i A[i][j] * rd_i
  float tc[3];
  float ie1, ie2, c21, Kq;
  float thr;       // 1.02 * exact circumscribed radius^2
  float vis0;      // vis at near point (beta=0, pixel-independent)
};

// log2 f, f = (y0^(1/e2)+y1^(1/e2))^(e2/e1) + y2^(1/e1), y = q^2+1e-12
__device__ __forceinline__ float lf_eval(float q0, float q1, float q2,
                                         float ie1, float ie2, float c21) {
  const float y0 = fmaf(q0, q0, 1e-12f);
  const float y1 = fmaf(q1, q1, 1e-12f);
  const float y2 = fmaf(q2, q2, 1e-12f);
  const float la = ie2 * __builtin_amdgcn_logf(y0);
  const float lb = ie2 * __builtin_amdgcn_logf(y1);
  const float lc = ie1 * __builtin_amdgcn_logf(y2);
  const float mab = fmaxf(la, lb), nab = fminf(la, lb);
  const float lab = mab + __builtin_amdgcn_logf(1.0f + __builtin_amdgcn_exp2f(nab - mab));
  const float lg = c21 * lab;
  const float mf = fmaxf(lg, lc), nf = fminf(lg, lc);
  return mf + __builtin_amdgcn_logf(1.0f + __builtin_amdgcn_exp2f(nf - mf));
}

__device__ __forceinline__ float point_ev(float b, float w0, float w1, float w2,
                                          float tc0, float tc1, float tc2,
                                          float ie1, float ie2, float c21, float Kq) {
  const float lf = lf_eval(fmaf(b, w0, tc0), fmaf(b, w1, tc1), fmaf(b, w2, tc2),
                           ie1, ie2, c21);
  const float occ = __builtin_amdgcn_rcpf(1.0f + __builtin_amdgcn_exp2f(Kq * lf));
  return __builtin_amdgcn_exp2f(-TAU2 * occ);
}

// full body for one (lane,SQ) hit entry; returns depth and src lane
__device__ __forceinline__ void body_compute(
    int e, const SQT* __restrict__ sq,
    const float* __restrict__ rdx, const float* __restrict__ rdy,
    const float* __restrict__ rdz, float& depth_out, int& src_out) {
  const int src = e & 63;
  const int n = e >> 6;
  const SQT& q = sq[n];
  const float urd0 = rdx[src], urd1 = rdy[src], urd2 = rdz[src];

  const float w0 = q.A[0] * urd0 + q.A[3] * urd1 + q.A[6] * urd2;
  const float w1 = q.A[1] * urd0 + q.A[4] * urd1 + q.A[7] * urd2;
  const float w2 = q.A[2] * urd0 + q.A[5] * urd1 + q.A[8] * urd2;
  const float tc0 = q.tc[0], tc1 = q.tc[1], tc2 = q.tc[2];

  const float lam2 = w0 * w0 + w1 * w1 + w2 * w2;
  const float dd = tc0 * w0 + tc1 * w1 + tc2 * w2;
  const float pb = fabsf(dd) * __builtin_amdgcn_rcpf(lam2);
  const float ce0 = fmaf(pb, w0, tc0);
  const float ce1 = fmaf(pb, w1, tc1);
  const float ce2 = fmaf(pb, w2, tc2);
  const float dist2 = ce0 * ce0 + ce1 * ce1 + ce2 * ce2;
  const float hb = sqrtf(fmaxf(3.0f - dist2, 1e-12f)) * rsqrtf(lam2);
  const float ie1 = q.ie1, ie2 = q.ie2, c21 = q.c21, Kq = q.Kq;
  const float thr = q.thr;

  // saturation proofs (valid when dd<=0, perpendicular foot):
  // |q(t)|^2 = dist2 + t^2*(3-dist2) > thr -> F >= 1.02 -> ev = 1 (to 3.5e-7)
  const float h3 = 3.0f - dist2;
  const bool ddneg = dd <= 0.0f;
  const bool sat18 = ddneg && (fmaf(h3, T2_18, dist2) > thr);
  const bool sat27 = ddneg && (fmaf(h3, T2_27, dist2) > thr);

  float evv[8];
#pragma unroll
  for (int i = 0; i < 8; i++) evv[i] = 1.0f;

  if (__all(sat27)) {                 // k=1,2,7,8 provably saturated
#pragma unroll
    for (int k = 3; k <= 6; k++) {
      const float b = fmaf(fmaf((float)k, DT9, -1.0f), hb, pb);
      evv[k - 1] = point_ev(b, w0, w1, w2, tc0, tc1, tc2, ie1, ie2, c21, Kq);
    }
  } else if (__all(sat18)) {          // k=1,8 provably saturated
#pragma unroll
    for (int k = 2; k <= 7; k++) {
      const float b = fmaf(fmaf((float)k, DT9, -1.0f), hb, pb);
      evv[k - 1] = point_ev(b, w0, w1, w2, tc0, tc1, tc2, ie1, ie2, c21, Kq);
    }
  } else {
#pragma unroll
    for (int k = 1; k <= 8; k++) {
      const float b = fmaf(fmaf((float)k, DT9, -1.0f), hb, pb);
      evv[k - 1] = point_ev(b, w0, w1, w2, tc0, tc1, tc2, ie1, ie2, c21, Kq);
    }
  }

  // chord endpoints k=0,9: |q|^2 = 3 exactly when dd<=0 -> ev = 1;
  // dd>0 (mirrored foot) breaks the identity; wave-uniform rare path.
  float ev0 = 1.0f, ev9 = 1.0f;
  if (__any(dd > 0.0f)) {
    ev0 = point_ev(pb - hb, w0, w1, w2, tc0, tc1, tc2, ie1, ie2, c21, Kq);
    ev9 = point_ev(pb + hb, w0, w1, w2, tc0, tc1, tc2, ie1, ie2, c21, Kq);
  }
  // far point (beta=FAR): F >= 1.06 -> ev = 1 always. Deleted.

  float v = q.vis0;
  float vn = v * ev0;
  float depth = (v + vn) * fabsf(pb - hb);      // near segment
  v = vn;
  float mid = 0.0f;
#pragma unroll
  for (int k = 1; k <= 8; k++) { vn = v * evv[k - 1]; mid += v + vn; v = vn; }
  vn = v * ev9; mid += v + vn; v = vn;           // segment 8->9
  depth += mid * (hb * DT9);                     // 9 uniform interior segments
  depth += (v + v) * fabsf(FARV - pb - hb);      // far segment (ev_far = 1)
  depth *= 0.5f;

  depth_out = depth;
  src_out = src;
}

// block = 1 wave; in-LDS compaction of (lane,SQ) hit pairs, dense body rounds
__global__ __launch_bounds__(64) void depth_kernel(
    const float* __restrict__ poses, const float* __restrict__ params,
    const float* __restrict__ rays_d, const float* __restrict__ rays_o,
    float* __restrict__ out)
{
  __shared__ SQT sq[NSQ];
  __shared__ float rdx[64], rdy[64], rdz[64];
  __shared__ unsigned short list[64 * NSQ];
  __shared__ int dmin[64];

  const int tid = threadIdx.x;
  const int pix = blockIdx.x * 64 + tid;

  // (b) issue ray loads first: HBM latency overlaps the whole prologue
  const float rd0 = rays_d[pix * 3 + 0];
  const float rd1 = rays_d[pix * 3 + 1];
  const float rd2 = rays_d[pix * 3 + 2];

  // (c) split prologue: A/tc/thr before barrier; vis0 chain deferred
  float tcr0 = 0.f, tcr1 = 0.f, tcr2 = 0.f, ie1r = 0.f, ie2r = 0.f, c21r = 0.f, Kqr = 0.f;
  if (tid < NSQ) {
    const float* P = poses + tid * 16;
    const float* par = params + tid * 5;
    const float is0 = 1.0f / par[0], is1 = 1.0f / par[1], is2 = 1.0f / par[2];
    const float e1 = par[3], e2 = par[4];
    SQT q;
    q.A[0] = P[0] * is0;  q.A[1] = P[1] * is1;  q.A[2] = P[2]  * is2;
    q.A[3] = P[4] * is0;  q.A[4] = P[5] * is1;  q.A[5] = P[6]  * is2;
    q.A[6] = P[8] * is0;  q.A[7] = P[9] * is1;  q.A[8] = P[10] * is2;
    const float d0 = rays_o[0] - P[3], d1 = rays_o[1] - P[7], d2 = rays_o[2] - P[11];
    tcr0 = q.A[0] * d0 + q.A[3] * d1 + q.A[6] * d2;
    tcr1 = q.A[1] * d0 + q.A[4] * d1 + q.A[7] * d2;
    tcr2 = q.A[2] * d0 + q.A[5] * d1 + q.A[8] * d2;
    q.tc[0] = tcr0; q.tc[1] = tcr1; q.tc[2] = tcr2;
    ie1r = 1.0f / e1; ie2r = 1.0f / e2; c21r = e2 * ie1r; Kqr = SHARPV * e1;
    q.ie1 = ie1r; q.ie2 = ie2r; q.c21 = c21r; q.Kq = Kqr;
    // exact circumscribed radius^2 of F=1 surface (squared-coord frame)
    const float c = __builtin_amdgcn_exp2f(1.0f - e2);
    const float V1 = (e1 < 1.0f) ? __builtin_amdgcn_exp2f(1.0f - e1) : 1.0f;
    float V2;
    if (e1 < 0.999f) {
      const float cp = __builtin_amdgcn_exp2f((1.0f - e2) / (1.0f - e1));
      V2 = __builtin_amdgcn_exp2f((1.0f - e1) * __builtin_amdgcn_logf(1.0f + cp));
    } else {
      V2 = fmaxf(c, 1.0f);
    }
    q.thr = 1.02f * fmaxf(V1, V2);
    q.vis0 = 1.0f;                       // patched after cull
    sq[tid] = q;
  }
  rdx[tid] = rd0; rdy[tid] = rd1; rdz[tid] = rd2;
  dmin[tid] = __float_as_int(FARV);
  __syncthreads();

  // (c) start vis0's long trans chain now; latency hides under cull VALU
  float lf0 = 0.0f;
  if (tid < NSQ) lf0 = lf_eval(tcr0, tcr1, tcr2, ie1r, ie2r, c21r);

  // ---- phase 1: cull all 8 SQs, ballot-pack hits into LDS list ----
  int H = 0;
#pragma unroll
  for (int n = 0; n < NSQ; n++) {
    const SQT& q = sq[n];   // uniform -> broadcast
    const float w0 = q.A[0] * rd0 + q.A[3] * rd1 + q.A[6] * rd2;
    const float w1 = q.A[1] * rd0 + q.A[4] * rd1 + q.A[7] * rd2;
    const float w2 = q.A[2] * rd0 + q.A[5] * rd1 + q.A[8] * rd2;
    const float lam2 = w0 * w0 + w1 * w1 + w2 * w2;
    const float dd = q.tc[0] * w0 + q.tc[1] * w1 + q.tc[2] * w2;
    const float pb = fabsf(dd) * __builtin_amdgcn_rcpf(lam2);
    const float ce0 = fmaf(pb, w0, q.tc[0]);
    const float ce1 = fmaf(pb, w1, q.tc[1]);
    const float ce2 = fmaf(pb, w2, q.tc[2]);
    const float dist2 = ce0 * ce0 + ce1 * ce1 + ce2 * ce2;
    const bool hit = dist2 < q.thr;
    const unsigned long long b = __ballot(hit);
    if (hit) {
      const int pos = H + __popcll(b & ((1ull << tid) - 1ull));
      list[pos] = (unsigned short)(tid | (n << 6));
    }
    H += __popcll(b);
  }

  // (c) finish vis0 and patch the table
  if (tid < NSQ) {
    const float occ0 = __builtin_amdgcn_rcpf(1.0f + __builtin_amdgcn_exp2f(Kqr * lf0));
    sq[tid].vis0 = __builtin_amdgcn_exp2f(-TAU2 * occ0);
  }
  __syncthreads();   // orders list writes + vis0 patch before phase 2

  // ---- phase 2: dense body rounds, 2 entries per lane per round (ILP) ----
  for (int j = tid; j < H; j += 128) {
    const int jb = j + 64;
    const bool hasB = jb < H;
    const int eA = list[j];
    const int eB = list[hasB ? jb : j];   // clamped dup in tail round
    float dA, dB; int sA, sB;
    body_compute(eA, sq, rdx, rdy, rdz, dA, sA);
    body_compute(eB, sq, rdx, rdy, rdz, dB, sB);
    atomicMin(&dmin[sA], __float_as_int(dA));
    if (hasB) atomicMin(&dmin[sB], __float_as_int(dB));
  }
  __syncthreads();

  out[pix] = __int_as_float(dmin[tid]);
}

extern "C" void kernel_launch(void* const* d_in, const int* in_sizes, int n_in,
                              void* d_out, int out_size, void* d_ws, size_t ws_size,
                              hipStream_t stream) {
  const float* poses  = (const float*)d_in[0];
  const float* params = (const float*)d_in[1];
  const float* rays_d = (const float*)d_in[2];
  const float* rays_o = (const float*)d_in[3];

  depth_kernel<<<NPIX / 64, 64, 0, stream>>>(
      poses, params, rays_d, rays_o, (float*)d_out);
}

// Round 15
// 11.647 us; speedup vs baseline: 1.0444x; 1.0444x over previous
//
#include <hip/hip_runtime.h>

constexpr int NPIX = 360 * 640;            // 230400 = 3600 * 64 exactly
constexpr int NSQ = 8, NSAMP = 10;
constexpr float FARV = 1.5f;
constexpr float SHARPV = 1000.0f;
constexpr float TAU2 = 100.0f * 1.44269504f;   // TAU * log2(e)
constexpr float DT9 = 2.0f / 9.0f;
constexpr float T2_18 = 49.0f / 81.0f;     // t^2 at samples k=1,8
constexpr float T2_27 = 25.0f / 81.0f;     // t^2 at samples k=2,7

struct SQT {
  float A[9];      // R * diag(1/s):  w_j = sum_i A[i][j] * rd_i
  float tc[3];
  float ie1, ie2, c21, Kq;
  float thr;       // 1.02 * exact circumscribed radius^2
  float vis0;      // vis at near point (beta=0, pixel-independent)
};

// log2 f, f = (y0^(1/e2)+y1^(1/e2))^(e2/e1) + y2^(1/e1), y = q^2+1e-12
__device__ __forceinline__ float lf_eval(float q0, float q1, float q2,
                                         float ie1, float ie2, float c21) {
  const float y0 = fmaf(q0, q0, 1e-12f);
  const float y1 = fmaf(q1, q1, 1e-12f);
  const float y2 = fmaf(q2, q2, 1e-12f);
  const float la = ie2 * __builtin_amdgcn_logf(y0);
  const float lb = ie2 * __builtin_amdgcn_logf(y1);
  const float lc = ie1 * __builtin_amdgcn_logf(y2);
  const float mab = fmaxf(la, lb), nab = fminf(la, lb);
  const float lab = mab + __builtin_amdgcn_logf(1.0f + __builtin_amdgcn_exp2f(nab - mab));
  const float lg = c21 * lab;
  const float mf = fmaxf(lg, lc), nf = fminf(lg, lc);
  return mf + __builtin_amdgcn_logf(1.0f + __builtin_amdgcn_exp2f(nf - mf));
}

__device__ __forceinline__ SQT make_sqt(const float* __restrict__ P,
                                        const float* __restrict__ par,
                                        const float* __restrict__ rays_o) {
  const float is0 = 1.0f / par[0], is1 = 1.0f / par[1], is2 = 1.0f / par[2];
  const float e1 = par[3], e2 = par[4];
  SQT q;
  q.A[0] = P[0] * is0;  q.A[1] = P[1] * is1;  q.A[2] = P[2]  * is2;
  q.A[3] = P[4] * is0;  q.A[4] = P[5] * is1;  q.A[5] = P[6]  * is2;
  q.A[6] = P[8] * is0;  q.A[7] = P[9] * is1;  q.A[8] = P[10] * is2;
  const float d0 = rays_o[0] - P[3], d1 = rays_o[1] - P[7], d2 = rays_o[2] - P[11];
  q.tc[0] = q.A[0] * d0 + q.A[3] * d1 + q.A[6] * d2;
  q.tc[1] = q.A[1] * d0 + q.A[4] * d1 + q.A[7] * d2;
  q.tc[2] = q.A[2] * d0 + q.A[5] * d1 + q.A[8] * d2;
  q.ie1 = 1.0f / e1; q.ie2 = 1.0f / e2; q.c21 = e2 * q.ie1;
  q.Kq = SHARPV * e1;
  // exact circumscribed radius^2 of F=1 surface (squared-coord frame)
  const float c = __builtin_amdgcn_exp2f(1.0f - e2);
  const float V1 = (e1 < 1.0f) ? __builtin_amdgcn_exp2f(1.0f - e1) : 1.0f;
  float V2;
  if (e1 < 0.999f) {
    const float cp = __builtin_amdgcn_exp2f((1.0f - e2) / (1.0f - e1));
    V2 = __builtin_amdgcn_exp2f((1.0f - e1) * __builtin_amdgcn_logf(1.0f + cp));
  } else {
    V2 = fmaxf(c, 1.0f);
  }
  q.thr = 1.02f * fmaxf(V1, V2);
  const float lf0 = lf_eval(q.tc[0], q.tc[1], q.tc[2], q.ie1, q.ie2, q.c21);
  const float occ0 = __builtin_amdgcn_rcpf(1.0f + __builtin_amdgcn_exp2f(q.Kq * lf0));
  q.vis0 = __builtin_amdgcn_exp2f(-TAU2 * occ0);
  return q;
}

__device__ __forceinline__ float point_ev(float b, float w0, float w1, float w2,
                                          float tc0, float tc1, float tc2,
                                          float ie1, float ie2, float c21, float Kq) {
  const float lf = lf_eval(fmaf(b, w0, tc0), fmaf(b, w1, tc1), fmaf(b, w2, tc2),
                           ie1, ie2, c21);
  const float occ = __builtin_amdgcn_rcpf(1.0f + __builtin_amdgcn_exp2f(Kq * lf));
  return __builtin_amdgcn_exp2f(-TAU2 * occ);
}

// block = 1 wave; in-LDS compaction of (lane,SQ) hit pairs, dense body rounds
__global__ __launch_bounds__(64) void depth_kernel(
    const float* __restrict__ poses, const float* __restrict__ params,
    const float* __restrict__ rays_d, const float* __restrict__ rays_o,
    float* __restrict__ out)
{
  __shared__ SQT sq[NSQ];
  __shared__ float rdx[64], rdy[64], rdz[64];
  __shared__ unsigned short list[64 * NSQ];
  __shared__ int dmin[64];

  const int tid = threadIdx.x;
  if (tid < NSQ) sq[tid] = make_sqt(poses + tid * 16, params + tid * 5, rays_o);

  const int pix = blockIdx.x * 64 + tid;
  const float rd0 = rays_d[pix * 3 + 0];
  const float rd1 = rays_d[pix * 3 + 1];
  const float rd2 = rays_d[pix * 3 + 2];
  rdx[tid] = rd0; rdy[tid] = rd1; rdz[tid] = rd2;
  dmin[tid] = __float_as_int(FARV);
  __syncthreads();

  // ---- phase 1: cull all 8 SQs, ballot-pack hits into LDS list ----
  int H = 0;
#pragma unroll
  for (int n = 0; n < NSQ; n++) {
    const SQT& q = sq[n];   // uniform -> broadcast
    const float w0 = q.A[0] * rd0 + q.A[3] * rd1 + q.A[6] * rd2;
    const float w1 = q.A[1] * rd0 + q.A[4] * rd1 + q.A[7] * rd2;
    const float w2 = q.A[2] * rd0 + q.A[5] * rd1 + q.A[8] * rd2;
    const float lam2 = w0 * w0 + w1 * w1 + w2 * w2;
    const float dd = q.tc[0] * w0 + q.tc[1] * w1 + q.tc[2] * w2;
    const float pb = fabsf(dd) * __builtin_amdgcn_rcpf(lam2);
    const float ce0 = fmaf(pb, w0, q.tc[0]);
    const float ce1 = fmaf(pb, w1, q.tc[1]);
    const float ce2 = fmaf(pb, w2, q.tc[2]);
    const float dist2 = ce0 * ce0 + ce1 * ce1 + ce2 * ce2;
    const bool hit = dist2 < q.thr;
    const unsigned long long b = __ballot(hit);
    if (hit) {
      const int pos = H + __popcll(b & ((1ull << tid) - 1ull));
      list[pos] = (unsigned short)(tid | (n << 6));
    }
    H += __popcll(b);
  }
  __syncthreads();   // order ds_writes before cross-lane ds_reads

  // ---- phase 2: dense body rounds over the hit list ----
  for (int j = tid; j < H; j += 64) {
    const int e = list[j];
    const int src = e & 63;
    const int n = e >> 6;
    const SQT& q = sq[n];             // per-lane indexed LDS gather
    const float urd0 = rdx[src], urd1 = rdy[src], urd2 = rdz[src];

    const float w0 = q.A[0] * urd0 + q.A[3] * urd1 + q.A[6] * urd2;
    const float w1 = q.A[1] * urd0 + q.A[4] * urd1 + q.A[7] * urd2;
    const float w2 = q.A[2] * urd0 + q.A[5] * urd1 + q.A[8] * urd2;
    const float tc0 = q.tc[0], tc1 = q.tc[1], tc2 = q.tc[2];

    const float lam2 = w0 * w0 + w1 * w1 + w2 * w2;
    const float dd = tc0 * w0 + tc1 * w1 + tc2 * w2;
    const float pb = fabsf(dd) * __builtin_amdgcn_rcpf(lam2);
    const float ce0 = fmaf(pb, w0, tc0);
    const float ce1 = fmaf(pb, w1, tc1);
    const float ce2 = fmaf(pb, w2, tc2);
    const float dist2 = ce0 * ce0 + ce1 * ce1 + ce2 * ce2;
    const float hb = sqrtf(fmaxf(3.0f - dist2, 1e-12f)) * rsqrtf(lam2);
    const float ie1 = q.ie1, ie2 = q.ie2, c21 = q.c21, Kq = q.Kq;
    const float thr = q.thr;

    // saturation proofs (valid when dd<=0, perpendicular foot):
    // |q(t)|^2 = dist2 + t^2*(3-dist2) > thr  ->  F >= 1.02 -> t >= 28.6 -> ev = 1
    const float h3 = 3.0f - dist2;
    const bool ddneg = dd <= 0.0f;
    const bool sat18 = ddneg && (fmaf(h3, T2_18, dist2) > thr);
    const bool sat27 = ddneg && (fmaf(h3, T2_27, dist2) > thr);

    float evv[8];
#pragma unroll
    for (int i = 0; i < 8; i++) evv[i] = 1.0f;

    if (__all(sat27)) {                 // k=1,2,7,8 provably saturated
#pragma unroll
      for (int k = 3; k <= 6; k++) {
        const float b = fmaf(fmaf((float)k, DT9, -1.0f), hb, pb);
        evv[k - 1] = point_ev(b, w0, w1, w2, tc0, tc1, tc2, ie1, ie2, c21, Kq);
      }
    } else if (__all(sat18)) {          // k=1,8 provably saturated
#pragma unroll
      for (int k = 2; k <= 7; k++) {
        const float b = fmaf(fmaf((float)k, DT9, -1.0f), hb, pb);
        evv[k - 1] = point_ev(b, w0, w1, w2, tc0, tc1, tc2, ie1, ie2, c21, Kq);
      }
    } else {
#pragma unroll
      for (int k = 1; k <= 8; k++) {
        const float b = fmaf(fmaf((float)k, DT9, -1.0f), hb, pb);
        evv[k - 1] = point_ev(b, w0, w1, w2, tc0, tc1, tc2, ie1, ie2, c21, Kq);
      }
    }

    // chord endpoints k=0,9: |q|^2 = 3 exactly when dd<=0 -> ev = 1;
    // dd>0 (mirrored foot) breaks the identity; wave-uniform rare path.
    float ev0 = 1.0f, ev9 = 1.0f;
    if (__any(dd > 0.0f)) {
      ev0 = point_ev(pb - hb, w0, w1, w2, tc0, tc1, tc2, ie1, ie2, c21, Kq);
      ev9 = point_ev(pb + hb, w0, w1, w2, tc0, tc1, tc2, ie1, ie2, c21, Kq);
    }
    // far point (beta=FAR): F >= 1.06 -> ev = 1 always. Deleted.

    float v = q.vis0;
    float vn = v * ev0;
    float depth = (v + vn) * fabsf(pb - hb);      // near segment
    v = vn;
    float mid = 0.0f;
#pragma unroll
    for (int k = 1; k <= 8; k++) { vn = v * evv[k - 1]; mid += v + vn; v = vn; }
    vn = v * ev9; mid += v + vn; v = vn;           // segment 8->9
    depth += mid * (hb * DT9);                     // 9 uniform interior segments
    depth += (v + v) * fabsf(FARV - pb - hb);      // far segment (ev_far = 1)
    depth *= 0.5f;

    atomicMin(&dmin[src], __float_as_int(depth));  // LDS atomic, exact
  }
  __syncthreads();

  out[pix] = __int_as_float(dmin[tid]);
}

extern "C" void kernel_launch(void* const* d_in, const int* in_sizes, int n_in,
                              void* d_out, int out_size, void* d_ws, size_t ws_size,
                              hipStream_t stream) {
  const float* poses  = (const float*)d_in[0];
  const float* params = (const float*)d_in[1];
  const float* rays_d = (const float*)d_in[2];
  const float* rays_o = (const float*)d_in[3];

  depth_kernel<<<NPIX / 64, 64, 0, stream>>>(
      poses, params, rays_d, rays_o, (float*)d_out);
}